// Round 4
// baseline (583.054 us; speedup 1.0000x reference)
//
#include <hip/hip_runtime.h>
#include <math.h>

// LinkPredictor fused MLP for MI355X (gfx950) — round 4.
// vs round 3:
//  * fused_edges: 48-edge tiles, LDS shrunk to exactly 49152 B (X2 + layer-4
//    scratch aliased into the X1 region, biases read from global) -> 3
//    blocks/CU (was 2) for gather/compute overlap; gather de-duplicated
//    (round 3 loaded every edge twice).
//  * precompute: single merged kernel computes Ha and Hb in one pass over z
//    (reads z once, not twice), two 64-neuron register passes to stay <=128 VGPR.

typedef _Float16 f16x8 __attribute__((ext_vector_type(8)));
typedef _Float16 f16x4 __attribute__((ext_vector_type(4)));
typedef float    f32x4 __attribute__((ext_vector_type(4)));

#define W1E (512*512)
#define W2E (256*512)
#define W3E (256*256)
#define WTOT (W1E+W2E+W3E)
#define H_OFF 1048576   // byte offset of H in d_ws

// Repack W[N][K] fp32 -> f16 MFMA A-fragment stream:
// dst[((ntile*(K/32)+ktile)*64 + lane)*8 + j] = W[ntile*16+(lane&15)][ktile*32+(lane>>4)*8+j]
__global__ void repack_w(const float* __restrict__ W1, const float* __restrict__ W2,
                         const float* __restrict__ W3, _Float16* __restrict__ wout) {
  int t = blockIdx.x * 256 + threadIdx.x;
  if (t >= WTOT) return;
  const float* src; _Float16* dst; int K, idx;
  if (t < W1E)            { src = W1; K = 512; idx = t;             dst = wout; }
  else if (t < W1E + W2E) { src = W2; K = 512; idx = t - W1E;       dst = wout + W1E; }
  else                    { src = W3; K = 256; idx = t - (W1E+W2E); dst = wout + W1E + W2E; }
  int j    = idx & 7;
  int lane = (idx >> 3) & 63;
  int rest = idx >> 9;
  int ktiles = K >> 5;
  int kt = rest % ktiles;
  int nt = rest / ktiles;
  int n = nt * 16 + (lane & 15);
  int k = kt * 32 + (lane >> 4) * 8 + j;
  dst[idx] = (_Float16)src[n * K + k];
}

// ---------------- merged precompute:
// H[n][1024] = [ Ha = W1[:, :256] z[n] + b1  |  Hb = W1[:, 256:] z[n] ]
// 512 threads, 64 nodes/block. Wave wid: half = wid>>2 (0=Ha,1=Hb),
// wloc = wid&3 -> neurons wloc*128..+127 of that half, in two passes of 64.
__global__ __launch_bounds__(512, 4)
void precompute_h2(const float* __restrict__ z, int N, const float* __restrict__ b1,
                   const _Float16* __restrict__ w1, _Float16* __restrict__ H) {
  __shared__ char smem[32768];     // z block [64][256] f16, stride 512B, swizzled
  const int tid  = threadIdx.x;
  const int wid  = tid >> 6;
  const int lane = tid & 63;
  const int l15  = lane & 15;
  const int lhi  = lane >> 4;
  const int nbase = blockIdx.x * 64;
  const int half = wid >> 2;       // 0 -> Ha, 1 -> Hb
  const int wloc = wid & 3;

  for (int r = wid; r < 64; r += 8) {
    int n = nbase + r; if (n >= N) n = N - 1;
    float4 v = *(const float4*)(z + (size_t)n * 256 + lane * 4);
    f16x4 h;
    h[0] = (_Float16)v.x; h[1] = (_Float16)v.y; h[2] = (_Float16)v.z; h[3] = (_Float16)v.w;
    *(f16x4*)(smem + r * 512 + ((lane * 8) ^ ((r & 7) << 4))) = h;
  }
  __syncthreads();

  for (int p = 0; p < 2; ++p) {
    f32x4 acc[4][4];
    #pragma unroll
    for (int nt = 0; nt < 4; ++nt) {
      f32x4 bv = (f32x4){0.f, 0.f, 0.f, 0.f};
      if (half == 0) bv = *(const f32x4*)(b1 + wloc*128 + p*64 + nt*16 + lhi*4);
      #pragma unroll
      for (int et = 0; et < 4; ++et) acc[nt][et] = bv;
    }

    for (int kt = 0; kt < 8; ++kt) {
      int ktg = kt + half * 8;
      f16x8 wf[4], xf[4];
      #pragma unroll
      for (int nt = 0; nt < 4; ++nt) {
        int ntg = wloc*8 + p*4 + nt;
        wf[nt] = *(const f16x8*)(w1 + (((ntg*16 + ktg)*64 + lane)) * 8);
      }
      #pragma unroll
      for (int et = 0; et < 4; ++et) {
        int r = et*16 + l15;
        xf[et] = *(const f16x8*)(smem + r * 512 + ((kt*64 + lhi*16) ^ ((r & 7) << 4)));
      }
      #pragma unroll
      for (int nt = 0; nt < 4; ++nt)
        #pragma unroll
        for (int et = 0; et < 4; ++et)
          acc[nt][et] = __builtin_amdgcn_mfma_f32_16x16x32_f16(wf[nt], xf[et], acc[nt][et], 0, 0, 0);
    }

    #pragma unroll
    for (int nt = 0; nt < 4; ++nt)
      #pragma unroll
      for (int et = 0; et < 4; ++et) {
        int n = nbase + et*16 + l15;
        if (n < N) {
          f16x4 h;
          #pragma unroll
          for (int r = 0; r < 4; ++r) h[r] = (_Float16)acc[nt][et][r];
          *(f16x4*)(H + (size_t)n * 1024 + half*512 + wloc*128 + p*64 + nt*16 + lhi*4) = h;
        }
      }
  }
}

// ---------------- fused edge kernel: X1 = relu(Ha[row]+Hb[col]) -> layers 2/3/4
// 48 edges/block. LDS = 49152 B total:
//   X1 [48][512] f16 stride 1024B (swizzled)          [0, 49152)
//   X2 [48][256] f16 stride 512B  (aliased, post-L2)  [0, 24576)
//   scr [48][8] f32 (aliased into dead X1 mid-region) [24576, 26112)
#define SCR_OFF  24576
#define LDS2_BYTES 49152

__global__ __launch_bounds__(512, 6)
void fused_edges48(const int* __restrict__ ei, int E, const _Float16* __restrict__ H,
                   const float* __restrict__ b2, const float* __restrict__ b3,
                   const float* __restrict__ W4, const float* __restrict__ b4,
                   const _Float16* __restrict__ w2, const _Float16* __restrict__ w3,
                   float* __restrict__ out) {
  extern __shared__ char smem[];
  float* scr = (float*)(smem + SCR_OFF);

  const int tid  = threadIdx.x;
  const int wid  = tid >> 6;
  const int lane = tid & 63;
  const int l15  = lane & 15;
  const int lhi  = lane >> 4;
  const int base = blockIdx.x * 48;

  // ---- gather: one pass per edge (6 iters/wave), full 1KB X1 row per iter
  #pragma unroll 3
  for (int e = wid; e < 48; e += 8) {
    int ge = base + e; if (ge >= E) ge = E - 1;
    int nr = ei[ge];
    int nc = ei[E + ge];
    f16x8 ha = *(const f16x8*)(H + (size_t)nr * 1024 + lane * 8);
    f16x8 hb = *(const f16x8*)(H + (size_t)nc * 1024 + 512 + lane * 8);
    f16x8 s = ha + hb;
    #pragma unroll
    for (int j = 0; j < 8; ++j) s[j] = (s[j] > (_Float16)0) ? s[j] : (_Float16)0;
    *(f16x8*)(smem + e * 1024 + ((lane * 16) ^ ((e & 7) << 4))) = s;
  }
  __syncthreads();

  // ---------- layer2: wave owns neurons wid*32..+31, all 48 edges (K=512)
  f32x4 acc2[2][3];
  #pragma unroll
  for (int nt = 0; nt < 2; ++nt) {
    f32x4 bv = *(const f32x4*)(b2 + wid*32 + nt*16 + lhi*4);
    #pragma unroll
    for (int et = 0; et < 3; ++et) acc2[nt][et] = bv;
  }
  for (int kt = 0; kt < 16; ++kt) {
    f16x8 wf[2], xf[3];
    #pragma unroll
    for (int nt = 0; nt < 2; ++nt)
      wf[nt] = *(const f16x8*)(w2 + (((wid*2 + nt)*16 + kt)*64 + lane) * 8);
    #pragma unroll
    for (int et = 0; et < 3; ++et) {
      int e = et*16 + l15;
      xf[et] = *(const f16x8*)(smem + e * 1024 + ((kt*64 + lhi*16) ^ ((e & 7) << 4)));
    }
    #pragma unroll
    for (int nt = 0; nt < 2; ++nt)
      #pragma unroll
      for (int et = 0; et < 3; ++et)
        acc2[nt][et] = __builtin_amdgcn_mfma_f32_16x16x32_f16(wf[nt], xf[et], acc2[nt][et], 0, 0, 0);
  }
  __syncthreads();   // all X1 reads done; X2 region overwrites below
  #pragma unroll
  for (int nt = 0; nt < 2; ++nt)
    #pragma unroll
    for (int et = 0; et < 3; ++et) {
      int e = et*16 + l15;
      int ncb = (wid*32 + nt*16 + lhi*4) * 2;
      f16x4 h;
      #pragma unroll
      for (int r = 0; r < 4; ++r) h[r] = (_Float16)fmaxf(acc2[nt][et][r], 0.f);
      *(f16x4*)(smem + e * 512 + (ncb ^ ((e & 7) << 4))) = h;
    }
  __syncthreads();

  // ---------- layer3: wave owns neurons wid*32..+31, all 48 edges (K=256)
  f32x4 acc3[2][3];
  #pragma unroll
  for (int nt = 0; nt < 2; ++nt) {
    f32x4 bv = *(const f32x4*)(b3 + wid*32 + nt*16 + lhi*4);
    #pragma unroll
    for (int et = 0; et < 3; ++et) acc3[nt][et] = bv;
  }
  for (int kt = 0; kt < 8; ++kt) {
    f16x8 wf[2], xf[3];
    #pragma unroll
    for (int nt = 0; nt < 2; ++nt)
      wf[nt] = *(const f16x8*)(w3 + (((wid*2 + nt)*8 + kt)*64 + lane) * 8);
    #pragma unroll
    for (int et = 0; et < 3; ++et) {
      int e = et*16 + l15;
      xf[et] = *(const f16x8*)(smem + e * 512 + ((kt*64 + lhi*16) ^ ((e & 7) << 4)));
    }
    #pragma unroll
    for (int nt = 0; nt < 2; ++nt)
      #pragma unroll
      for (int et = 0; et < 3; ++et)
        acc3[nt][et] = __builtin_amdgcn_mfma_f32_16x16x32_f16(wf[nt], xf[et], acc3[nt][et], 0, 0, 0);
  }

  // ---------- layer4: out = sigmoid(sum_n relu(X3)*w4 + b4)
  f32x4 w4v[2];
  #pragma unroll
  for (int nt = 0; nt < 2; ++nt)
    w4v[nt] = *(const f32x4*)(W4 + wid*32 + nt*16 + lhi*4);

  #pragma unroll
  for (int et = 0; et < 3; ++et) {
    float p = 0.f;
    #pragma unroll
    for (int nt = 0; nt < 2; ++nt)
      #pragma unroll
      for (int r = 0; r < 4; ++r)
        p += fmaxf(acc3[nt][et][r], 0.f) * w4v[nt][r];
    p += __shfl_xor(p, 16);
    p += __shfl_xor(p, 32);
    if (lane < 16) scr[(et*16 + l15) * 8 + wid] = p;
  }
  __syncthreads();

  if (tid < 48) {
    int ge = base + tid;
    if (ge < E) {
      float s = b4[0];
      #pragma unroll
      for (int w = 0; w < 8; ++w) s += scr[tid*8 + w];
      out[ge] = 1.f / (1.f + expf(-s));
    }
  }
}

// ---------------- fallback (ws too small): fully-fused single kernel
#define FSCR_OFF  65536
#define FBIAS_OFF 67584
#define FLDS_BYTES 72832

__global__ __launch_bounds__(512, 2)
void fused_fallback(const float* __restrict__ z, const int* __restrict__ ei, int E,
                    const float* __restrict__ b1, const float* __restrict__ b2,
                    const float* __restrict__ b3, const float* __restrict__ W4,
                    const float* __restrict__ b4,
                    const _Float16* __restrict__ wbuf, float* __restrict__ out) {
  extern __shared__ char smem[];
  float* scr = (float*)(smem + FSCR_OFF);
  float* bls = (float*)(smem + FBIAS_OFF);

  const int tid  = threadIdx.x;
  const int wid  = tid >> 6;
  const int lane = tid & 63;
  const int l15  = lane & 15;
  const int lhi  = lane >> 4;
  const int base = blockIdx.x * 64;

  for (int i = tid; i < 1281; i += 512) {
    float v;
    if (i < 512)       v = b1[i];
    else if (i < 768)  v = b2[i - 512];
    else if (i < 1024) v = b3[i - 768];
    else if (i < 1280) v = W4[i - 1024];
    else               v = b4[0];
    bls[i] = v;
  }

  for (int it = wid; it < 128; it += 8) {
    int e = it >> 1, hf = it & 1;
    int ge = base + e; if (ge >= E) ge = E - 1;
    int src = ei[hf ? (E + ge) : ge];
    float4 v = *(const float4*)(z + (size_t)src * 256 + lane * 4);
    f16x4 h;
    h[0] = (_Float16)v.x; h[1] = (_Float16)v.y; h[2] = (_Float16)v.z; h[3] = (_Float16)v.w;
    *(f16x4*)(smem + e * 1024 + ((hf * 512 + lane * 8) ^ ((e & 7) << 4))) = h;
  }
  __syncthreads();

  const _Float16* w1 = wbuf;
  const _Float16* w2 = wbuf + W1E;
  const _Float16* w3 = wbuf + W1E + W2E;

  f32x4 acc1[4][4];
  #pragma unroll
  for (int nt = 0; nt < 4; ++nt) {
    f32x4 bv = *(const f32x4*)(bls + wid*64 + nt*16 + lhi*4);
    #pragma unroll
    for (int et = 0; et < 4; ++et) acc1[nt][et] = bv;
  }
  for (int kt = 0; kt < 16; ++kt) {
    f16x8 wf[4], xf[4];
    #pragma unroll
    for (int nt = 0; nt < 4; ++nt)
      wf[nt] = *(const f16x8*)(w1 + (((wid*4 + nt)*16 + kt)*64 + lane) * 8);
    #pragma unroll
    for (int et = 0; et < 4; ++et) {
      int e = et*16 + l15;
      xf[et] = *(const f16x8*)(smem + e * 1024 + ((kt*64 + lhi*16) ^ ((e & 7) << 4)));
    }
    #pragma unroll
    for (int nt = 0; nt < 4; ++nt)
      #pragma unroll
      for (int et = 0; et < 4; ++et)
        acc1[nt][et] = __builtin_amdgcn_mfma_f32_16x16x32_f16(wf[nt], xf[et], acc1[nt][et], 0, 0, 0);
  }
  __syncthreads();
  #pragma unroll
  for (int nt = 0; nt < 4; ++nt)
    #pragma unroll
    for (int et = 0; et < 4; ++et) {
      int e = et*16 + l15;
      int ncb = (wid*64 + nt*16 + lhi*4) * 2;
      f16x4 h;
      #pragma unroll
      for (int r = 0; r < 4; ++r) h[r] = (_Float16)fmaxf(acc1[nt][et][r], 0.f);
      *(f16x4*)(smem + e * 1024 + (ncb ^ ((e & 7) << 4))) = h;
    }
  __syncthreads();

  f32x4 acc2[2][4];
  #pragma unroll
  for (int nt = 0; nt < 2; ++nt) {
    f32x4 bv = *(const f32x4*)(bls + 512 + wid*32 + nt*16 + lhi*4);
    #pragma unroll
    for (int et = 0; et < 4; ++et) acc2[nt][et] = bv;
  }
  for (int kt = 0; kt < 16; ++kt) {
    f16x8 wf[2], xf[4];
    #pragma unroll
    for (int nt = 0; nt < 2; ++nt)
      wf[nt] = *(const f16x8*)(w2 + (((wid*2 + nt)*16 + kt)*64 + lane) * 8);
    #pragma unroll
    for (int et = 0; et < 4; ++et) {
      int e = et*16 + l15;
      xf[et] = *(const f16x8*)(smem + e * 1024 + ((kt*64 + lhi*16) ^ ((e & 7) << 4)));
    }
    #pragma unroll
    for (int nt = 0; nt < 2; ++nt)
      #pragma unroll
      for (int et = 0; et < 4; ++et)
        acc2[nt][et] = __builtin_amdgcn_mfma_f32_16x16x32_f16(wf[nt], xf[et], acc2[nt][et], 0, 0, 0);
  }
  __syncthreads();
  #pragma unroll
  for (int nt = 0; nt < 2; ++nt)
    #pragma unroll
    for (int et = 0; et < 4; ++et) {
      int e = et*16 + l15;
      int ncb = (wid*32 + nt*16 + lhi*4) * 2;
      f16x4 h;
      #pragma unroll
      for (int r = 0; r < 4; ++r) h[r] = (_Float16)fmaxf(acc2[nt][et][r], 0.f);
      *(f16x4*)(smem + e * 512 + (ncb ^ ((e & 7) << 4))) = h;
    }
  __syncthreads();

  f32x4 acc3[2][4];
  #pragma unroll
  for (int nt = 0; nt < 2; ++nt) {
    f32x4 bv = *(const f32x4*)(bls + 768 + wid*32 + nt*16 + lhi*4);
    #pragma unroll
    for (int et = 0; et < 4; ++et) acc3[nt][et] = bv;
  }
  for (int kt = 0; kt < 8; ++kt) {
    f16x8 wf[2], xf[4];
    #pragma unroll
    for (int nt = 0; nt < 2; ++nt)
      wf[nt] = *(const f16x8*)(w3 + (((wid*2 + nt)*8 + kt)*64 + lane) * 8);
    #pragma unroll
    for (int et = 0; et < 4; ++et) {
      int e = et*16 + l15;
      xf[et] = *(const f16x8*)(smem + e * 512 + ((kt*64 + lhi*16) ^ ((e & 7) << 4)));
    }
    #pragma unroll
    for (int nt = 0; nt < 2; ++nt)
      #pragma unroll
      for (int et = 0; et < 4; ++et)
        acc3[nt][et] = __builtin_amdgcn_mfma_f32_16x16x32_f16(wf[nt], xf[et], acc3[nt][et], 0, 0, 0);
  }

  f32x4 w4v[2];
  #pragma unroll
  for (int nt = 0; nt < 2; ++nt)
    w4v[nt] = *(const f32x4*)(bls + 1024 + wid*32 + nt*16 + lhi*4);
  float bias4 = bls[1280];

  #pragma unroll
  for (int et = 0; et < 4; ++et) {
    float p = 0.f;
    #pragma unroll
    for (int nt = 0; nt < 2; ++nt)
      #pragma unroll
      for (int r = 0; r < 4; ++r)
        p += fmaxf(acc3[nt][et][r], 0.f) * w4v[nt][r];
    p += __shfl_xor(p, 16);
    p += __shfl_xor(p, 32);
    if (lane < 16) scr[(et*16 + l15) * 8 + wid] = p;
  }
  __syncthreads();

  if (tid < 64) {
    int ge = base + tid;
    if (ge < E) {
      float s = bias4;
      #pragma unroll
      for (int w = 0; w < 8; ++w) s += scr[tid*8 + w];
      out[ge] = 1.f / (1.f + expf(-s));
    }
  }
}

extern "C" void kernel_launch(void* const* d_in, const int* in_sizes, int n_in,
                              void* d_out, int out_size, void* d_ws, size_t ws_size,
                              hipStream_t stream) {
  const float* z  = (const float*)d_in[0];
  const int*   ei = (const int*)d_in[1];
  const float* W1 = (const float*)d_in[2];
  const float* b1 = (const float*)d_in[3];
  const float* W2 = (const float*)d_in[4];
  const float* b2 = (const float*)d_in[5];
  const float* W3 = (const float*)d_in[6];
  const float* b3 = (const float*)d_in[7];
  const float* W4 = (const float*)d_in[8];
  const float* b4 = (const float*)d_in[9];
  float* out = (float*)d_out;
  const int E = in_sizes[1] / 2;
  const int N = in_sizes[0] / 256;

  _Float16* wbuf = (_Float16*)d_ws;                      // 917504 B
  _Float16* H    = (_Float16*)((char*)d_ws + H_OFF);     // N*1024*2 B

  repack_w<<<(WTOT + 255) / 256, 256, 0, stream>>>(W1, W2, W3, wbuf);

  size_t need = (size_t)H_OFF + (size_t)N * 1024 * 2;
  if (ws_size >= need) {
    precompute_h2<<<(N + 63) / 64, 512, 0, stream>>>(z, N, b1, wbuf, H);
    int nblk = (E + 47) / 48;
    fused_edges48<<<nblk, 512, LDS2_BYTES, stream>>>(ei, E, H, b2, b3, W4, b4,
                                                     wbuf + W1E, wbuf + W1E + W2E, out);
  } else {
    int nblk = (E + 63) / 64;
    fused_fallback<<<nblk, 512, FLDS_BYTES, stream>>>(z, ei, E, b1, b2, b3, W4, b4, wbuf, out);
  }
}

// Round 5
// 416.758 us; speedup vs baseline: 1.3990x; 1.3990x over previous
//
#include <hip/hip_runtime.h>
#include <math.h>

// LinkPredictor fused MLP for MI355X (gfx950) — round 5.
// vs round 4: precompute_h2 __launch_bounds__(512,4) -> (512,2). Round 4's
// LB4 capped the register budget at ~128 while the hot loop keeps ~120 live
// (acc[4][4]=64 + wf/xf=32 + addressing) -> scratch spill (628 MB WRITE_SIZE,
// 465 MB FETCH, 350 us). Kernel is memory-bound (305 MB ideal), so register
// headroom > occupancy. Everything else unchanged.

typedef _Float16 f16x8 __attribute__((ext_vector_type(8)));
typedef _Float16 f16x4 __attribute__((ext_vector_type(4)));
typedef float    f32x4 __attribute__((ext_vector_type(4)));

#define W1E (512*512)
#define W2E (256*512)
#define W3E (256*256)
#define WTOT (W1E+W2E+W3E)
#define H_OFF 1048576   // byte offset of H in d_ws

// Repack W[N][K] fp32 -> f16 MFMA A-fragment stream:
// dst[((ntile*(K/32)+ktile)*64 + lane)*8 + j] = W[ntile*16+(lane&15)][ktile*32+(lane>>4)*8+j]
__global__ void repack_w(const float* __restrict__ W1, const float* __restrict__ W2,
                         const float* __restrict__ W3, _Float16* __restrict__ wout) {
  int t = blockIdx.x * 256 + threadIdx.x;
  if (t >= WTOT) return;
  const float* src; _Float16* dst; int K, idx;
  if (t < W1E)            { src = W1; K = 512; idx = t;             dst = wout; }
  else if (t < W1E + W2E) { src = W2; K = 512; idx = t - W1E;       dst = wout + W1E; }
  else                    { src = W3; K = 256; idx = t - (W1E+W2E); dst = wout + W1E + W2E; }
  int j    = idx & 7;
  int lane = (idx >> 3) & 63;
  int rest = idx >> 9;
  int ktiles = K >> 5;
  int kt = rest % ktiles;
  int nt = rest / ktiles;
  int n = nt * 16 + (lane & 15);
  int k = kt * 32 + (lane >> 4) * 8 + j;
  dst[idx] = (_Float16)src[n * K + k];
}

// ---------------- merged precompute:
// H[n][1024] = [ Ha = W1[:, :256] z[n] + b1  |  Hb = W1[:, 256:] z[n] ]
// 512 threads, 64 nodes/block. Wave wid: half = wid>>2 (0=Ha,1=Hb),
// wloc = wid&3 -> neurons wloc*128..+127 of that half, in two passes of 64.
// LB(512,2): 256-VGPR budget so acc[4][4]+wf+xf stay in registers (no spill).
__global__ __launch_bounds__(512, 2)
void precompute_h2(const float* __restrict__ z, int N, const float* __restrict__ b1,
                   const _Float16* __restrict__ w1, _Float16* __restrict__ H) {
  __shared__ char smem[32768];     // z block [64][256] f16, stride 512B, swizzled
  const int tid  = threadIdx.x;
  const int wid  = tid >> 6;
  const int lane = tid & 63;
  const int l15  = lane & 15;
  const int lhi  = lane >> 4;
  const int nbase = blockIdx.x * 64;
  const int half = wid >> 2;       // 0 -> Ha, 1 -> Hb
  const int wloc = wid & 3;

  for (int r = wid; r < 64; r += 8) {
    int n = nbase + r; if (n >= N) n = N - 1;
    float4 v = *(const float4*)(z + (size_t)n * 256 + lane * 4);
    f16x4 h;
    h[0] = (_Float16)v.x; h[1] = (_Float16)v.y; h[2] = (_Float16)v.z; h[3] = (_Float16)v.w;
    *(f16x4*)(smem + r * 512 + ((lane * 8) ^ ((r & 7) << 4))) = h;
  }
  __syncthreads();

  for (int p = 0; p < 2; ++p) {
    f32x4 acc[4][4];
    #pragma unroll
    for (int nt = 0; nt < 4; ++nt) {
      f32x4 bv = (f32x4){0.f, 0.f, 0.f, 0.f};
      if (half == 0) bv = *(const f32x4*)(b1 + wloc*128 + p*64 + nt*16 + lhi*4);
      #pragma unroll
      for (int et = 0; et < 4; ++et) acc[nt][et] = bv;
    }

    for (int kt = 0; kt < 8; ++kt) {
      int ktg = kt + half * 8;
      f16x8 wf[4], xf[4];
      #pragma unroll
      for (int nt = 0; nt < 4; ++nt) {
        int ntg = wloc*8 + p*4 + nt;
        wf[nt] = *(const f16x8*)(w1 + (((ntg*16 + ktg)*64 + lane)) * 8);
      }
      #pragma unroll
      for (int et = 0; et < 4; ++et) {
        int r = et*16 + l15;
        xf[et] = *(const f16x8*)(smem + r * 512 + ((kt*64 + lhi*16) ^ ((r & 7) << 4)));
      }
      #pragma unroll
      for (int nt = 0; nt < 4; ++nt)
        #pragma unroll
        for (int et = 0; et < 4; ++et)
          acc[nt][et] = __builtin_amdgcn_mfma_f32_16x16x32_f16(wf[nt], xf[et], acc[nt][et], 0, 0, 0);
    }

    #pragma unroll
    for (int nt = 0; nt < 4; ++nt)
      #pragma unroll
      for (int et = 0; et < 4; ++et) {
        int n = nbase + et*16 + l15;
        if (n < N) {
          f16x4 h;
          #pragma unroll
          for (int r = 0; r < 4; ++r) h[r] = (_Float16)acc[nt][et][r];
          *(f16x4*)(H + (size_t)n * 1024 + half*512 + wloc*128 + p*64 + nt*16 + lhi*4) = h;
        }
      }
  }
}

// ---------------- fused edge kernel: X1 = relu(Ha[row]+Hb[col]) -> layers 2/3/4
// 48 edges/block. LDS = 49152 B total:
//   X1 [48][512] f16 stride 1024B (swizzled)          [0, 49152)
//   X2 [48][256] f16 stride 512B  (aliased, post-L2)  [0, 24576)
//   scr [48][8] f32 (aliased into dead X1 mid-region) [24576, 26112)
#define SCR_OFF  24576
#define LDS2_BYTES 49152

__global__ __launch_bounds__(512, 6)
void fused_edges48(const int* __restrict__ ei, int E, const _Float16* __restrict__ H,
                   const float* __restrict__ b2, const float* __restrict__ b3,
                   const float* __restrict__ W4, const float* __restrict__ b4,
                   const _Float16* __restrict__ w2, const _Float16* __restrict__ w3,
                   float* __restrict__ out) {
  extern __shared__ char smem[];
  float* scr = (float*)(smem + SCR_OFF);

  const int tid  = threadIdx.x;
  const int wid  = tid >> 6;
  const int lane = tid & 63;
  const int l15  = lane & 15;
  const int lhi  = lane >> 4;
  const int base = blockIdx.x * 48;

  // ---- gather: one pass per edge (6 iters/wave), full 1KB X1 row per iter
  #pragma unroll 3
  for (int e = wid; e < 48; e += 8) {
    int ge = base + e; if (ge >= E) ge = E - 1;
    int nr = ei[ge];
    int nc = ei[E + ge];
    f16x8 ha = *(const f16x8*)(H + (size_t)nr * 1024 + lane * 8);
    f16x8 hb = *(const f16x8*)(H + (size_t)nc * 1024 + 512 + lane * 8);
    f16x8 s = ha + hb;
    #pragma unroll
    for (int j = 0; j < 8; ++j) s[j] = (s[j] > (_Float16)0) ? s[j] : (_Float16)0;
    *(f16x8*)(smem + e * 1024 + ((lane * 16) ^ ((e & 7) << 4))) = s;
  }
  __syncthreads();

  // ---------- layer2: wave owns neurons wid*32..+31, all 48 edges (K=512)
  f32x4 acc2[2][3];
  #pragma unroll
  for (int nt = 0; nt < 2; ++nt) {
    f32x4 bv = *(const f32x4*)(b2 + wid*32 + nt*16 + lhi*4);
    #pragma unroll
    for (int et = 0; et < 3; ++et) acc2[nt][et] = bv;
  }
  for (int kt = 0; kt < 16; ++kt) {
    f16x8 wf[2], xf[3];
    #pragma unroll
    for (int nt = 0; nt < 2; ++nt)
      wf[nt] = *(const f16x8*)(w2 + (((wid*2 + nt)*16 + kt)*64 + lane) * 8);
    #pragma unroll
    for (int et = 0; et < 3; ++et) {
      int e = et*16 + l15;
      xf[et] = *(const f16x8*)(smem + e * 1024 + ((kt*64 + lhi*16) ^ ((e & 7) << 4)));
    }
    #pragma unroll
    for (int nt = 0; nt < 2; ++nt)
      #pragma unroll
      for (int et = 0; et < 3; ++et)
        acc2[nt][et] = __builtin_amdgcn_mfma_f32_16x16x32_f16(wf[nt], xf[et], acc2[nt][et], 0, 0, 0);
  }
  __syncthreads();   // all X1 reads done; X2 region overwrites below
  #pragma unroll
  for (int nt = 0; nt < 2; ++nt)
    #pragma unroll
    for (int et = 0; et < 3; ++et) {
      int e = et*16 + l15;
      int ncb = (wid*32 + nt*16 + lhi*4) * 2;
      f16x4 h;
      #pragma unroll
      for (int r = 0; r < 4; ++r) h[r] = (_Float16)fmaxf(acc2[nt][et][r], 0.f);
      *(f16x4*)(smem + e * 512 + (ncb ^ ((e & 7) << 4))) = h;
    }
  __syncthreads();

  // ---------- layer3: wave owns neurons wid*32..+31, all 48 edges (K=256)
  f32x4 acc3[2][3];
  #pragma unroll
  for (int nt = 0; nt < 2; ++nt) {
    f32x4 bv = *(const f32x4*)(b3 + wid*32 + nt*16 + lhi*4);
    #pragma unroll
    for (int et = 0; et < 3; ++et) acc3[nt][et] = bv;
  }
  for (int kt = 0; kt < 8; ++kt) {
    f16x8 wf[2], xf[3];
    #pragma unroll
    for (int nt = 0; nt < 2; ++nt)
      wf[nt] = *(const f16x8*)(w3 + (((wid*2 + nt)*8 + kt)*64 + lane) * 8);
    #pragma unroll
    for (int et = 0; et < 3; ++et) {
      int e = et*16 + l15;
      xf[et] = *(const f16x8*)(smem + e * 512 + ((kt*64 + lhi*16) ^ ((e & 7) << 4)));
    }
    #pragma unroll
    for (int nt = 0; nt < 2; ++nt)
      #pragma unroll
      for (int et = 0; et < 3; ++et)
        acc3[nt][et] = __builtin_amdgcn_mfma_f32_16x16x32_f16(wf[nt], xf[et], acc3[nt][et], 0, 0, 0);
  }

  // ---------- layer4: out = sigmoid(sum_n relu(X3)*w4 + b4)
  f32x4 w4v[2];
  #pragma unroll
  for (int nt = 0; nt < 2; ++nt)
    w4v[nt] = *(const f32x4*)(W4 + wid*32 + nt*16 + lhi*4);

  #pragma unroll
  for (int et = 0; et < 3; ++et) {
    float p = 0.f;
    #pragma unroll
    for (int nt = 0; nt < 2; ++nt)
      #pragma unroll
      for (int r = 0; r < 4; ++r)
        p += fmaxf(acc3[nt][et][r], 0.f) * w4v[nt][r];
    p += __shfl_xor(p, 16);
    p += __shfl_xor(p, 32);
    if (lane < 16) scr[(et*16 + l15) * 8 + wid] = p;
  }
  __syncthreads();

  if (tid < 48) {
    int ge = base + tid;
    if (ge < E) {
      float s = b4[0];
      #pragma unroll
      for (int w = 0; w < 8; ++w) s += scr[tid*8 + w];
      out[ge] = 1.f / (1.f + expf(-s));
    }
  }
}

// ---------------- fallback (ws too small): fully-fused single kernel
#define FSCR_OFF  65536
#define FBIAS_OFF 67584
#define FLDS_BYTES 72832

__global__ __launch_bounds__(512, 2)
void fused_fallback(const float* __restrict__ z, const int* __restrict__ ei, int E,
                    const float* __restrict__ b1, const float* __restrict__ b2,
                    const float* __restrict__ b3, const float* __restrict__ W4,
                    const float* __restrict__ b4,
                    const _Float16* __restrict__ wbuf, float* __restrict__ out) {
  extern __shared__ char smem[];
  float* scr = (float*)(smem + FSCR_OFF);
  float* bls = (float*)(smem + FBIAS_OFF);

  const int tid  = threadIdx.x;
  const int wid  = tid >> 6;
  const int lane = tid & 63;
  const int l15  = lane & 15;
  const int lhi  = lane >> 4;
  const int base = blockIdx.x * 64;

  for (int i = tid; i < 1281; i += 512) {
    float v;
    if (i < 512)       v = b1[i];
    else if (i < 768)  v = b2[i - 512];
    else if (i < 1024) v = b3[i - 768];
    else if (i < 1280) v = W4[i - 1024];
    else               v = b4[0];
    bls[i] = v;
  }

  for (int it = wid; it < 128; it += 8) {
    int e = it >> 1, hf = it & 1;
    int ge = base + e; if (ge >= E) ge = E - 1;
    int src = ei[hf ? (E + ge) : ge];
    float4 v = *(const float4*)(z + (size_t)src * 256 + lane * 4);
    f16x4 h;
    h[0] = (_Float16)v.x; h[1] = (_Float16)v.y; h[2] = (_Float16)v.z; h[3] = (_Float16)v.w;
    *(f16x4*)(smem + e * 1024 + ((hf * 512 + lane * 8) ^ ((e & 7) << 4))) = h;
  }
  __syncthreads();

  const _Float16* w1 = wbuf;
  const _Float16* w2 = wbuf + W1E;
  const _Float16* w3 = wbuf + W1E + W2E;

  f32x4 acc1[4][4];
  #pragma unroll
  for (int nt = 0; nt < 4; ++nt) {
    f32x4 bv = *(const f32x4*)(bls + wid*64 + nt*16 + lhi*4);
    #pragma unroll
    for (int et = 0; et < 4; ++et) acc1[nt][et] = bv;
  }
  for (int kt = 0; kt < 16; ++kt) {
    f16x8 wf[4], xf[4];
    #pragma unroll
    for (int nt = 0; nt < 4; ++nt)
      wf[nt] = *(const f16x8*)(w1 + (((wid*4 + nt)*16 + kt)*64 + lane) * 8);
    #pragma unroll
    for (int et = 0; et < 4; ++et) {
      int e = et*16 + l15;
      xf[et] = *(const f16x8*)(smem + e * 1024 + ((kt*64 + lhi*16) ^ ((e & 7) << 4)));
    }
    #pragma unroll
    for (int nt = 0; nt < 4; ++nt)
      #pragma unroll
      for (int et = 0; et < 4; ++et)
        acc1[nt][et] = __builtin_amdgcn_mfma_f32_16x16x32_f16(wf[nt], xf[et], acc1[nt][et], 0, 0, 0);
  }
  __syncthreads();
  #pragma unroll
  for (int nt = 0; nt < 4; ++nt)
    #pragma unroll
    for (int et = 0; et < 4; ++et) {
      int e = et*16 + l15;
      int ncb = (wid*64 + nt*16 + lhi*4) * 2;
      f16x4 h;
      #pragma unroll
      for (int r = 0; r < 4; ++r) h[r] = (_Float16)fmaxf(acc1[nt][et][r], 0.f);
      *(f16x4*)(smem + e * 1024 + (ncb ^ ((e & 7) << 4))) = h;
    }
  __syncthreads();

  f32x4 acc2[2][4];
  #pragma unroll
  for (int nt = 0; nt < 2; ++nt) {
    f32x4 bv = *(const f32x4*)(bls + 512 + wid*32 + nt*16 + lhi*4);
    #pragma unroll
    for (int et = 0; et < 4; ++et) acc2[nt][et] = bv;
  }
  for (int kt = 0; kt < 16; ++kt) {
    f16x8 wf[2], xf[4];
    #pragma unroll
    for (int nt = 0; nt < 2; ++nt)
      wf[nt] = *(const f16x8*)(w2 + (((wid*2 + nt)*16 + kt)*64 + lane) * 8);
    #pragma unroll
    for (int et = 0; et < 4; ++et) {
      int e = et*16 + l15;
      xf[et] = *(const f16x8*)(smem + e * 1024 + ((kt*64 + lhi*16) ^ ((e & 7) << 4)));
    }
    #pragma unroll
    for (int nt = 0; nt < 2; ++nt)
      #pragma unroll
      for (int et = 0; et < 4; ++et)
        acc2[nt][et] = __builtin_amdgcn_mfma_f32_16x16x32_f16(wf[nt], xf[et], acc2[nt][et], 0, 0, 0);
  }
  __syncthreads();
  #pragma unroll
  for (int nt = 0; nt < 2; ++nt)
    #pragma unroll
    for (int et = 0; et < 4; ++et) {
      int e = et*16 + l15;
      int ncb = (wid*32 + nt*16 + lhi*4) * 2;
      f16x4 h;
      #pragma unroll
      for (int r = 0; r < 4; ++r) h[r] = (_Float16)fmaxf(acc2[nt][et][r], 0.f);
      *(f16x4*)(smem + e * 512 + (ncb ^ ((e & 7) << 4))) = h;
    }
  __syncthreads();

  f32x4 acc3[2][4];
  #pragma unroll
  for (int nt = 0; nt < 2; ++nt) {
    f32x4 bv = *(const f32x4*)(bls + 768 + wid*32 + nt*16 + lhi*4);
    #pragma unroll
    for (int et = 0; et < 4; ++et) acc3[nt][et] = bv;
  }
  for (int kt = 0; kt < 8; ++kt) {
    f16x8 wf[2], xf[4];
    #pragma unroll
    for (int nt = 0; nt < 2; ++nt)
      wf[nt] = *(const f16x8*)(w3 + (((wid*2 + nt)*8 + kt)*64 + lane) * 8);
    #pragma unroll
    for (int et = 0; et < 4; ++et) {
      int e = et*16 + l15;
      xf[et] = *(const f16x8*)(smem + e * 512 + ((kt*64 + lhi*16) ^ ((e & 7) << 4)));
    }
    #pragma unroll
    for (int nt = 0; nt < 2; ++nt)
      #pragma unroll
      for (int et = 0; et < 4; ++et)
        acc3[nt][et] = __builtin_amdgcn_mfma_f32_16x16x32_f16(wf[nt], xf[et], acc3[nt][et], 0, 0, 0);
  }

  f32x4 w4v[2];
  #pragma unroll
  for (int nt = 0; nt < 2; ++nt)
    w4v[nt] = *(const f32x4*)(bls + 1024 + wid*32 + nt*16 + lhi*4);
  float bias4 = bls[1280];

  #pragma unroll
  for (int et = 0; et < 4; ++et) {
    float p = 0.f;
    #pragma unroll
    for (int nt = 0; nt < 2; ++nt)
      #pragma unroll
      for (int r = 0; r < 4; ++r)
        p += fmaxf(acc3[nt][et][r], 0.f) * w4v[nt][r];
    p += __shfl_xor(p, 16);
    p += __shfl_xor(p, 32);
    if (lane < 16) scr[(et*16 + l15) * 8 + wid] = p;
  }
  __syncthreads();

  if (tid < 64) {
    int ge = base + tid;
    if (ge < E) {
      float s = bias4;
      #pragma unroll
      for (int w = 0; w < 8; ++w) s += scr[tid*8 + w];
      out[ge] = 1.f / (1.f + expf(-s));
    }
  }
}

extern "C" void kernel_launch(void* const* d_in, const int* in_sizes, int n_in,
                              void* d_out, int out_size, void* d_ws, size_t ws_size,
                              hipStream_t stream) {
  const float* z  = (const float*)d_in[0];
  const int*   ei = (const int*)d_in[1];
  const float* W1 = (const float*)d_in[2];
  const float* b1 = (const float*)d_in[3];
  const float* W2 = (const float*)d_in[4];
  const float* b2 = (const float*)d_in[5];
  const float* W3 = (const float*)d_in[6];
  const float* b3 = (const float*)d_in[7];
  const float* W4 = (const float*)d_in[8];
  const float* b4 = (const float*)d_in[9];
  float* out = (float*)d_out;
  const int E = in_sizes[1] / 2;
  const int N = in_sizes[0] / 256;

  _Float16* wbuf = (_Float16*)d_ws;                      // 917504 B
  _Float16* H    = (_Float16*)((char*)d_ws + H_OFF);     // N*1024*2 B

  repack_w<<<(WTOT + 255) / 256, 256, 0, stream>>>(W1, W2, W3, wbuf);

  size_t need = (size_t)H_OFF + (size_t)N * 1024 * 2;
  if (ws_size >= need) {
    precompute_h2<<<(N + 63) / 64, 512, 0, stream>>>(z, N, b1, wbuf, H);
    int nblk = (E + 47) / 48;
    fused_edges48<<<nblk, 512, LDS2_BYTES, stream>>>(ei, E, H, b2, b3, W4, b4,
                                                     wbuf + W1E, wbuf + W1E + W2E, out);
  } else {
    int nblk = (E + 63) / 64;
    fused_fallback<<<nblk, 512, FLDS_BYTES, stream>>>(z, ei, E, b1, b2, b3, W4, b4, wbuf, out);
  }
}

// Round 6
// 409.205 us; speedup vs baseline: 1.4248x; 1.0185x over previous
//
#include <hip/hip_runtime.h>
#include <math.h>

// LinkPredictor fused MLP for MI355X (gfx950) — round 6.
// vs round 5:
//  * precompute_h2: H stores were 64-way scattered (8B per lane at 2KB stride,
//    MFMA C/D layout). Now each wave transposes its 64neuron x 64node tile
//    through a private 4KB LDS staging area (two 32-neuron rounds, swizzled,
//    no barriers) and writes H as coalesced 64B-line stores.
//  * fused_edges48: #pragma unroll 2 on layer-2/3 kt loops so the compiler
//    pipelines the per-iteration L2 weight loads across iterations.

typedef _Float16 f16x8 __attribute__((ext_vector_type(8)));
typedef _Float16 f16x4 __attribute__((ext_vector_type(4)));
typedef float    f32x4 __attribute__((ext_vector_type(4)));

#define W1E (512*512)
#define W2E (256*512)
#define W3E (256*256)
#define WTOT (W1E+W2E+W3E)
#define H_OFF 1048576   // byte offset of H in d_ws

// Repack W[N][K] fp32 -> f16 MFMA A-fragment stream:
// dst[((ntile*(K/32)+ktile)*64 + lane)*8 + j] = W[ntile*16+(lane&15)][ktile*32+(lane>>4)*8+j]
__global__ void repack_w(const float* __restrict__ W1, const float* __restrict__ W2,
                         const float* __restrict__ W3, _Float16* __restrict__ wout) {
  int t = blockIdx.x * 256 + threadIdx.x;
  if (t >= WTOT) return;
  const float* src; _Float16* dst; int K, idx;
  if (t < W1E)            { src = W1; K = 512; idx = t;             dst = wout; }
  else if (t < W1E + W2E) { src = W2; K = 512; idx = t - W1E;       dst = wout + W1E; }
  else                    { src = W3; K = 256; idx = t - (W1E+W2E); dst = wout + W1E + W2E; }
  int j    = idx & 7;
  int lane = (idx >> 3) & 63;
  int rest = idx >> 9;
  int ktiles = K >> 5;
  int kt = rest % ktiles;
  int nt = rest / ktiles;
  int n = nt * 16 + (lane & 15);
  int k = kt * 32 + (lane >> 4) * 8 + j;
  dst[idx] = (_Float16)src[n * K + k];
}

// ---------------- merged precompute:
// H[n][1024] = [ Ha = W1[:, :256] z[n] + b1  |  Hb = W1[:, 256:] z[n] ]
// 512 threads, 64 nodes/block. Wave wid: half = wid>>2 (0=Ha,1=Hb),
// wloc = wid&3 -> neurons wloc*128..+127 of that half, two passes p of 64.
// H write path: per-wave LDS transpose staging (4KB private), coalesced
// 64B-line global stores.
__global__ __launch_bounds__(512, 2)
void precompute_h2(const float* __restrict__ z, int N, const float* __restrict__ b1,
                   const _Float16* __restrict__ w1, _Float16* __restrict__ H) {
  __shared__ char smem[65536];     // [0,32768): z [64][256] f16 swz; [32768,65536): staging 8x4KB
  const int tid  = threadIdx.x;
  const int wid  = tid >> 6;
  const int lane = tid & 63;
  const int l15  = lane & 15;
  const int lhi  = lane >> 4;
  const int nbase = blockIdx.x * 64;
  const int half = wid >> 2;       // 0 -> Ha, 1 -> Hb
  const int wloc = wid & 3;
  char* stg = smem + 32768 + wid * 4096;   // per-wave private

  for (int r = wid; r < 64; r += 8) {
    int n = nbase + r; if (n >= N) n = N - 1;
    float4 v = *(const float4*)(z + (size_t)n * 256 + lane * 4);
    f16x4 h;
    h[0] = (_Float16)v.x; h[1] = (_Float16)v.y; h[2] = (_Float16)v.z; h[3] = (_Float16)v.w;
    *(f16x4*)(smem + r * 512 + ((lane * 8) ^ ((r & 7) << 4))) = h;
  }
  __syncthreads();

  for (int p = 0; p < 2; ++p) {
    f32x4 acc[4][4];
    #pragma unroll
    for (int nt = 0; nt < 4; ++nt) {
      f32x4 bv = (f32x4){0.f, 0.f, 0.f, 0.f};
      if (half == 0) bv = *(const f32x4*)(b1 + wloc*128 + p*64 + nt*16 + lhi*4);
      #pragma unroll
      for (int et = 0; et < 4; ++et) acc[nt][et] = bv;
    }

    for (int kt = 0; kt < 8; ++kt) {
      int ktg = kt + half * 8;
      f16x8 wf[4], xf[4];
      #pragma unroll
      for (int nt = 0; nt < 4; ++nt) {
        int ntg = wloc*8 + p*4 + nt;
        wf[nt] = *(const f16x8*)(w1 + (((ntg*16 + ktg)*64 + lane)) * 8);
      }
      #pragma unroll
      for (int et = 0; et < 4; ++et) {
        int r = et*16 + l15;
        xf[et] = *(const f16x8*)(smem + r * 512 + ((kt*64 + lhi*16) ^ ((r & 7) << 4)));
      }
      #pragma unroll
      for (int nt = 0; nt < 4; ++nt)
        #pragma unroll
        for (int et = 0; et < 4; ++et)
          acc[nt][et] = __builtin_amdgcn_mfma_f32_16x16x32_f16(wf[nt], xf[et], acc[nt][et], 0, 0, 0);
    }

    // ---- write-out via per-wave LDS transpose staging, 2 rounds x 32 neurons
    #pragma unroll
    for (int ntp = 0; ntp < 2; ++ntp) {
      #pragma unroll
      for (int nt2 = 0; nt2 < 2; ++nt2) {
        int nt = ntp*2 + nt2;
        #pragma unroll
        for (int et = 0; et < 4; ++et) {
          int node = et*16 + l15;
          f16x4 h;
          #pragma unroll
          for (int r = 0; r < 4; ++r) h[r] = (_Float16)acc[nt][et][r];
          int off = nt2*32 + lhi*8;                       // byte offset within 64B strip
          *(f16x4*)(stg + node*64 + (off ^ ((node & 3) << 4))) = h;
        }
      }
      // same-wave RAW: compiler inserts lgkmcnt; region is wave-private (no barrier)
      #pragma unroll
      for (int i = 0; i < 4; ++i) {
        int node = i*16 + (lane >> 2);
        int off  = (lane & 3) * 16;
        f16x8 v = *(const f16x8*)(stg + node*64 + (off ^ ((node & 3) << 4)));
        int gn = nbase + node;
        if (gn < N)
          *(f16x8*)(H + (size_t)gn*1024 + half*512 + wloc*128 + p*64 + ntp*32 + (lane & 3)*8) = v;
      }
    }
  }
}

// ---------------- fused edge kernel: X1 = relu(Ha[row]+Hb[col]) -> layers 2/3/4
// 48 edges/block. LDS = 49152 B total:
//   X1 [48][512] f16 stride 1024B (swizzled)          [0, 49152)
//   X2 [48][256] f16 stride 512B  (aliased, post-L2)  [0, 24576)
//   scr [48][8] f32 (aliased into dead X1 mid-region) [24576, 26112)
#define SCR_OFF  24576
#define LDS2_BYTES 49152

__global__ __launch_bounds__(512, 6)
void fused_edges48(const int* __restrict__ ei, int E, const _Float16* __restrict__ H,
                   const float* __restrict__ b2, const float* __restrict__ b3,
                   const float* __restrict__ W4, const float* __restrict__ b4,
                   const _Float16* __restrict__ w2, const _Float16* __restrict__ w3,
                   float* __restrict__ out) {
  extern __shared__ char smem[];
  float* scr = (float*)(smem + SCR_OFF);

  const int tid  = threadIdx.x;
  const int wid  = tid >> 6;
  const int lane = tid & 63;
  const int l15  = lane & 15;
  const int lhi  = lane >> 4;
  const int base = blockIdx.x * 48;

  // ---- gather: one pass per edge (6 iters/wave), full 1KB X1 row per iter
  #pragma unroll 3
  for (int e = wid; e < 48; e += 8) {
    int ge = base + e; if (ge >= E) ge = E - 1;
    int nr = ei[ge];
    int nc = ei[E + ge];
    f16x8 ha = *(const f16x8*)(H + (size_t)nr * 1024 + lane * 8);
    f16x8 hb = *(const f16x8*)(H + (size_t)nc * 1024 + 512 + lane * 8);
    f16x8 s = ha + hb;
    #pragma unroll
    for (int j = 0; j < 8; ++j) s[j] = (s[j] > (_Float16)0) ? s[j] : (_Float16)0;
    *(f16x8*)(smem + e * 1024 + ((lane * 16) ^ ((e & 7) << 4))) = s;
  }
  __syncthreads();

  // ---------- layer2: wave owns neurons wid*32..+31, all 48 edges (K=512)
  f32x4 acc2[2][3];
  #pragma unroll
  for (int nt = 0; nt < 2; ++nt) {
    f32x4 bv = *(const f32x4*)(b2 + wid*32 + nt*16 + lhi*4);
    #pragma unroll
    for (int et = 0; et < 3; ++et) acc2[nt][et] = bv;
  }
  #pragma unroll 2
  for (int kt = 0; kt < 16; ++kt) {
    f16x8 wf[2], xf[3];
    #pragma unroll
    for (int nt = 0; nt < 2; ++nt)
      wf[nt] = *(const f16x8*)(w2 + (((wid*2 + nt)*16 + kt)*64 + lane) * 8);
    #pragma unroll
    for (int et = 0; et < 3; ++et) {
      int e = et*16 + l15;
      xf[et] = *(const f16x8*)(smem + e * 1024 + ((kt*64 + lhi*16) ^ ((e & 7) << 4)));
    }
    #pragma unroll
    for (int nt = 0; nt < 2; ++nt)
      #pragma unroll
      for (int et = 0; et < 3; ++et)
        acc2[nt][et] = __builtin_amdgcn_mfma_f32_16x16x32_f16(wf[nt], xf[et], acc2[nt][et], 0, 0, 0);
  }
  __syncthreads();   // all X1 reads done; X2 region overwrites below
  #pragma unroll
  for (int nt = 0; nt < 2; ++nt)
    #pragma unroll
    for (int et = 0; et < 3; ++et) {
      int e = et*16 + l15;
      int ncb = (wid*32 + nt*16 + lhi*4) * 2;
      f16x4 h;
      #pragma unroll
      for (int r = 0; r < 4; ++r) h[r] = (_Float16)fmaxf(acc2[nt][et][r], 0.f);
      *(f16x4*)(smem + e * 512 + (ncb ^ ((e & 7) << 4))) = h;
    }
  __syncthreads();

  // ---------- layer3: wave owns neurons wid*32..+31, all 48 edges (K=256)
  f32x4 acc3[2][3];
  #pragma unroll
  for (int nt = 0; nt < 2; ++nt) {
    f32x4 bv = *(const f32x4*)(b3 + wid*32 + nt*16 + lhi*4);
    #pragma unroll
    for (int et = 0; et < 3; ++et) acc3[nt][et] = bv;
  }
  #pragma unroll 2
  for (int kt = 0; kt < 8; ++kt) {
    f16x8 wf[2], xf[3];
    #pragma unroll
    for (int nt = 0; nt < 2; ++nt)
      wf[nt] = *(const f16x8*)(w3 + (((wid*2 + nt)*8 + kt)*64 + lane) * 8);
    #pragma unroll
    for (int et = 0; et < 3; ++et) {
      int e = et*16 + l15;
      xf[et] = *(const f16x8*)(smem + e * 512 + ((kt*64 + lhi*16) ^ ((e & 7) << 4)));
    }
    #pragma unroll
    for (int nt = 0; nt < 2; ++nt)
      #pragma unroll
      for (int et = 0; et < 3; ++et)
        acc3[nt][et] = __builtin_amdgcn_mfma_f32_16x16x32_f16(wf[nt], xf[et], acc3[nt][et], 0, 0, 0);
  }

  // ---------- layer4: out = sigmoid(sum_n relu(X3)*w4 + b4)
  f32x4 w4v[2];
  #pragma unroll
  for (int nt = 0; nt < 2; ++nt)
    w4v[nt] = *(const f32x4*)(W4 + wid*32 + nt*16 + lhi*4);

  #pragma unroll
  for (int et = 0; et < 3; ++et) {
    float p = 0.f;
    #pragma unroll
    for (int nt = 0; nt < 2; ++nt)
      #pragma unroll
      for (int r = 0; r < 4; ++r)
        p += fmaxf(acc3[nt][et][r], 0.f) * w4v[nt][r];
    p += __shfl_xor(p, 16);
    p += __shfl_xor(p, 32);
    if (lane < 16) scr[(et*16 + l15) * 8 + wid] = p;
  }
  __syncthreads();

  if (tid < 48) {
    int ge = base + tid;
    if (ge < E) {
      float s = b4[0];
      #pragma unroll
      for (int w = 0; w < 8; ++w) s += scr[tid*8 + w];
      out[ge] = 1.f / (1.f + expf(-s));
    }
  }
}

// ---------------- fallback (ws too small): fully-fused single kernel
#define FSCR_OFF  65536
#define FBIAS_OFF 67584
#define FLDS_BYTES 72832

__global__ __launch_bounds__(512, 2)
void fused_fallback(const float* __restrict__ z, const int* __restrict__ ei, int E,
                    const float* __restrict__ b1, const float* __restrict__ b2,
                    const float* __restrict__ b3, const float* __restrict__ W4,
                    const float* __restrict__ b4,
                    const _Float16* __restrict__ wbuf, float* __restrict__ out) {
  extern __shared__ char smem[];
  float* scr = (float*)(smem + FSCR_OFF);
  float* bls = (float*)(smem + FBIAS_OFF);

  const int tid  = threadIdx.x;
  const int wid  = tid >> 6;
  const int lane = tid & 63;
  const int l15  = lane & 15;
  const int lhi  = lane >> 4;
  const int base = blockIdx.x * 64;

  for (int i = tid; i < 1281; i += 512) {
    float v;
    if (i < 512)       v = b1[i];
    else if (i < 768)  v = b2[i - 512];
    else if (i < 1024) v = b3[i - 768];
    else if (i < 1280) v = W4[i - 1024];
    else               v = b4[0];
    bls[i] = v;
  }

  for (int it = wid; it < 128; it += 8) {
    int e = it >> 1, hf = it & 1;
    int ge = base + e; if (ge >= E) ge = E - 1;
    int src = ei[hf ? (E + ge) : ge];
    float4 v = *(const float4*)(z + (size_t)src * 256 + lane * 4);
    f16x4 h;
    h[0] = (_Float16)v.x; h[1] = (_Float16)v.y; h[2] = (_Float16)v.z; h[3] = (_Float16)v.w;
    *(f16x4*)(smem + e * 1024 + ((hf * 512 + lane * 8) ^ ((e & 7) << 4))) = h;
  }
  __syncthreads();

  const _Float16* w1 = wbuf;
  const _Float16* w2 = wbuf + W1E;
  const _Float16* w3 = wbuf + W1E + W2E;

  f32x4 acc1[4][4];
  #pragma unroll
  for (int nt = 0; nt < 4; ++nt) {
    f32x4 bv = *(const f32x4*)(bls + wid*64 + nt*16 + lhi*4);
    #pragma unroll
    for (int et = 0; et < 4; ++et) acc1[nt][et] = bv;
  }
  for (int kt = 0; kt < 16; ++kt) {
    f16x8 wf[4], xf[4];
    #pragma unroll
    for (int nt = 0; nt < 4; ++nt)
      wf[nt] = *(const f16x8*)(w1 + (((wid*4 + nt)*16 + kt)*64 + lane) * 8);
    #pragma unroll
    for (int et = 0; et < 4; ++et) {
      int e = et*16 + l15;
      xf[et] = *(const f16x8*)(smem + e * 1024 + ((kt*64 + lhi*16) ^ ((e & 7) << 4)));
    }
    #pragma unroll
    for (int nt = 0; nt < 4; ++nt)
      #pragma unroll
      for (int et = 0; et < 4; ++et)
        acc1[nt][et] = __builtin_amdgcn_mfma_f32_16x16x32_f16(wf[nt], xf[et], acc1[nt][et], 0, 0, 0);
  }
  __syncthreads();
  #pragma unroll
  for (int nt = 0; nt < 4; ++nt)
    #pragma unroll
    for (int et = 0; et < 4; ++et) {
      int e = et*16 + l15;
      int ncb = (wid*64 + nt*16 + lhi*4) * 2;
      f16x4 h;
      #pragma unroll
      for (int r = 0; r < 4; ++r) h[r] = (_Float16)fmaxf(acc1[nt][et][r], 0.f);
      *(f16x4*)(smem + e * 1024 + (ncb ^ ((e & 7) << 4))) = h;
    }
  __syncthreads();

  f32x4 acc2[2][4];
  #pragma unroll
  for (int nt = 0; nt < 2; ++nt) {
    f32x4 bv = *(const f32x4*)(bls + 512 + wid*32 + nt*16 + lhi*4);
    #pragma unroll
    for (int et = 0; et < 4; ++et) acc2[nt][et] = bv;
  }
  for (int kt = 0; kt < 16; ++kt) {
    f16x8 wf[2], xf[4];
    #pragma unroll
    for (int nt = 0; nt < 2; ++nt)
      wf[nt] = *(const f16x8*)(w2 + (((wid*2 + nt)*16 + kt)*64 + lane) * 8);
    #pragma unroll
    for (int et = 0; et < 4; ++et) {
      int e = et*16 + l15;
      xf[et] = *(const f16x8*)(smem + e * 1024 + ((kt*64 + lhi*16) ^ ((e & 7) << 4)));
    }
    #pragma unroll
    for (int nt = 0; nt < 2; ++nt)
      #pragma unroll
      for (int et = 0; et < 4; ++et)
        acc2[nt][et] = __builtin_amdgcn_mfma_f32_16x16x32_f16(wf[nt], xf[et], acc2[nt][et], 0, 0, 0);
  }
  __syncthreads();
  #pragma unroll
  for (int nt = 0; nt < 2; ++nt)
    #pragma unroll
    for (int et = 0; et < 4; ++et) {
      int e = et*16 + l15;
      int ncb = (wid*32 + nt*16 + lhi*4) * 2;
      f16x4 h;
      #pragma unroll
      for (int r = 0; r < 4; ++r) h[r] = (_Float16)fmaxf(acc2[nt][et][r], 0.f);
      *(f16x4*)(smem + e * 512 + (ncb ^ ((e & 7) << 4))) = h;
    }
  __syncthreads();

  f32x4 acc3[2][4];
  #pragma unroll
  for (int nt = 0; nt < 2; ++nt) {
    f32x4 bv = *(const f32x4*)(bls + 768 + wid*32 + nt*16 + lhi*4);
    #pragma unroll
    for (int et = 0; et < 4; ++et) acc3[nt][et] = bv;
  }
  for (int kt = 0; kt < 8; ++kt) {
    f16x8 wf[2], xf[4];
    #pragma unroll
    for (int nt = 0; nt < 2; ++nt)
      wf[nt] = *(const f16x8*)(w3 + (((wid*2 + nt)*8 + kt)*64 + lane) * 8);
    #pragma unroll
    for (int et = 0; et < 4; ++et) {
      int e = et*16 + l15;
      xf[et] = *(const f16x8*)(smem + e * 512 + ((kt*64 + lhi*16) ^ ((e & 7) << 4)));
    }
    #pragma unroll
    for (int nt = 0; nt < 2; ++nt)
      #pragma unroll
      for (int et = 0; et < 4; ++et)
        acc3[nt][et] = __builtin_amdgcn_mfma_f32_16x16x32_f16(wf[nt], xf[et], acc3[nt][et], 0, 0, 0);
  }

  f32x4 w4v[2];
  #pragma unroll
  for (int nt = 0; nt < 2; ++nt)
    w4v[nt] = *(const f32x4*)(bls + 1024 + wid*32 + nt*16 + lhi*4);
  float bias4 = bls[1280];

  #pragma unroll
  for (int et = 0; et < 4; ++et) {
    float p = 0.f;
    #pragma unroll
    for (int nt = 0; nt < 2; ++nt)
      #pragma unroll
      for (int r = 0; r < 4; ++r)
        p += fmaxf(acc3[nt][et][r], 0.f) * w4v[nt][r];
    p += __shfl_xor(p, 16);
    p += __shfl_xor(p, 32);
    if (lane < 16) scr[(et*16 + l15) * 8 + wid] = p;
  }
  __syncthreads();

  if (tid < 64) {
    int ge = base + tid;
    if (ge < E) {
      float s = bias4;
      #pragma unroll
      for (int w = 0; w < 8; ++w) s += scr[tid*8 + w];
      out[ge] = 1.f / (1.f + expf(-s));
    }
  }
}

extern "C" void kernel_launch(void* const* d_in, const int* in_sizes, int n_in,
                              void* d_out, int out_size, void* d_ws, size_t ws_size,
                              hipStream_t stream) {
  const float* z  = (const float*)d_in[0];
  const int*   ei = (const int*)d_in[1];
  const float* W1 = (const float*)d_in[2];
  const float* b1 = (const float*)d_in[3];
  const float* W2 = (const float*)d_in[4];
  const float* b2 = (const float*)d_in[5];
  const float* W3 = (const float*)d_in[6];
  const float* b3 = (const float*)d_in[7];
  const float* W4 = (const float*)d_in[8];
  const float* b4 = (const float*)d_in[9];
  float* out = (float*)d_out;
  const int E = in_sizes[1] / 2;
  const int N = in_sizes[0] / 256;

  _Float16* wbuf = (_Float16*)d_ws;                      // 917504 B
  _Float16* H    = (_Float16*)((char*)d_ws + H_OFF);     // N*1024*2 B

  repack_w<<<(WTOT + 255) / 256, 256, 0, stream>>>(W1, W2, W3, wbuf);

  size_t need = (size_t)H_OFF + (size_t)N * 1024 * 2;
  if (ws_size >= need) {
    precompute_h2<<<(N + 63) / 64, 512, 0, stream>>>(z, N, b1, wbuf, H);
    int nblk = (E + 47) / 48;
    fused_edges48<<<nblk, 512, LDS2_BYTES, stream>>>(ei, E, H, b2, b3, W4, b4,
                                                     wbuf + W1E, wbuf + W1E + W2E, out);
  } else {
    int nblk = (E + 63) / 64;
    fused_fallback<<<nblk, 512, FLDS_BYTES, stream>>>(z, ei, E, b1, b2, b3, W4, b4, wbuf, out);
  }
}